// Round 1
// baseline (1132.796 us; speedup 1.0000x reference)
//
#include <hip/hip_runtime.h>

// Linear (e3nn-style): irreps 256x0e + 256x1o + 256x2e, B=50000.
// Y[z,w,i] = (1/16) * sum_u W[u,w] * X[z,u,i]  per block d in {1,3,5}.
//
// Strategy: memory-bound streaming GEMM with bf16 MFMA.
//  - Pre-kernel: Wt[b][w][u] = bf16(W[b][u][w] / 16) into d_ws (393216 B).
//  - Main kernel: no LDS, no barriers. Each wave: M=16 rows of m=(z,i),
//    N=256 (full, so features are read from HBM exactly once), K=256 in
//    8 steps of mfma_f32_16x16x32_bf16.
//  - A-fragment: 8 stride-d scalar global loads per lane (d=1: 2x float4),
//    converted to bf16 RNE in registers. L1 absorbs the stride-d overfetch
//    because neighboring m-rows / k-groups of the same wave use the rest
//    of each line.
//  - B-fragment: 16B vector load from pre-transposed Wt (L1/L2-hot).

typedef __attribute__((ext_vector_type(8))) short bf16x8;
typedef __attribute__((ext_vector_type(4))) float f32x4;

#define NB1 782   // ceil(50000*1/64)
#define NB3 2344  // ceil(50000*3/64)
#define NB5 3907  // ceil(50000*5/64)

__device__ __forceinline__ unsigned short f2bf(float f) {
  union { float f; unsigned u; } x; x.f = f;
  unsigned u = x.u;
  return (unsigned short)((u + 0x7FFFu + ((u >> 16) & 1u)) >> 16);
}

__global__ void convert_weights(const float* __restrict__ w,
                                unsigned short* __restrict__ wt) {
  int idx = blockIdx.x * 256 + threadIdx.x;  // 196608 total, exact grid
  int b = idx >> 16;       // block 0,1,2
  int r = idx & 65535;
  int wc = r >> 8;         // output-channel index (row of Wt)
  int u = r & 255;         // input-channel index (contiguous in Wt)
  float v = w[(b << 16) + u * 256 + wc] * 0.0625f;  // fold 1/sqrt(256)
  wt[idx] = f2bf(v);
}

template <int D>
__device__ __forceinline__ void gemm_body(const float* __restrict__ feat,
                                          const unsigned short* __restrict__ wt,
                                          float* __restrict__ out, int mtile) {
  constexpr int XOFF = (D == 1) ? 0 : (D == 3) ? 256 : 1024;      // elem offset in 2304-row
  constexpr int WOFF = (D == 1) ? 0 : (D == 3) ? 65536 : 131072;  // elem offset in Wt
  constexpr int MP = 50000 * D;  // rows of flattened m=(z,i)

  const int tid = threadIdx.x;
  const int wave = tid >> 6;
  const int lane = tid & 63;
  const int col = lane & 15;  // MFMA n (and A-row m for loads)
  const int kg = lane >> 4;   // MFMA k-group (and C row-group)
  const int mb = mtile * 64 + wave * 16;

  // A-load row for this lane (clamped; invalid rows are masked at store)
  int mA = mb + col;
  if (mA > MP - 1) mA = MP - 1;
  const int zA = mA / D;
  const int iA = mA - zA * D;
  const float* aptr = feat + (size_t)zA * 2304 + XOFF + iA;  // stride D along u

  const unsigned short* wbase = wt + WOFF + col * 256;

  f32x4 acc[16];
#pragma unroll
  for (int n = 0; n < 16; ++n) acc[n] = (f32x4){0.f, 0.f, 0.f, 0.f};

  for (int kk = 0; kk < 8; ++kk) {
    const int k0 = kk * 32 + kg * 8;
    float v[8];
    if constexpr (D == 1) {
      const f32x4* p = (const f32x4*)(aptr + k0);
      f32x4 lo = p[0];
      f32x4 hi = p[1];
#pragma unroll
      for (int j = 0; j < 4; ++j) { v[j] = lo[j]; v[4 + j] = hi[j]; }
    } else {
#pragma unroll
      for (int j = 0; j < 8; ++j) v[j] = aptr[(k0 + j) * D];
    }
    bf16x8 a;
#pragma unroll
    for (int j = 0; j < 8; ++j) a[j] = (short)f2bf(v[j]);

#pragma unroll
    for (int nf = 0; nf < 16; ++nf) {
      bf16x8 b = *(const bf16x8*)(wbase + nf * 4096 + k0);  // Wt[w=nf*16+col][k0..k0+7]
      acc[nf] = __builtin_amdgcn_mfma_f32_16x16x32_bf16(a, b, acc[nf], 0, 0, 0);
    }
  }

  // C/D layout (verified m89/m91): n = lane&15, m = (lane>>4)*4 + reg
#pragma unroll
  for (int r = 0; r < 4; ++r) {
    int m = mb + kg * 4 + r;
    if (m < MP) {
      int z = m / D;
      int i = m - z * D;
      float* op = out + (size_t)z * 2304 + XOFF + i + col * D;
#pragma unroll
      for (int nf = 0; nf < 16; ++nf) {
        op[nf * 16 * D] = acc[nf][r];
      }
    }
  }
}

__global__ __launch_bounds__(256, 3) void linear_kernel(
    const float* __restrict__ feat, const unsigned short* __restrict__ wt,
    float* __restrict__ out) {
  int bid = blockIdx.x;
  if (bid < NB1) {
    gemm_body<1>(feat, wt, out, bid);
  } else if (bid < NB1 + NB3) {
    gemm_body<3>(feat, wt, out, bid - NB1);
  } else {
    gemm_body<5>(feat, wt, out, bid - NB1 - NB3);
  }
}

extern "C" void kernel_launch(void* const* d_in, const int* in_sizes, int n_in,
                              void* d_out, int out_size, void* d_ws, size_t ws_size,
                              hipStream_t stream) {
  const float* feat = (const float*)d_in[0];      // (50000, 2304) fp32
  const float* w = (const float*)d_in[1];         // (196608,) fp32
  float* out = (float*)d_out;                     // (50000, 2304) fp32
  unsigned short* wt = (unsigned short*)d_ws;     // 196608 bf16 = 393216 B

  hipLaunchKernelGGL(convert_weights, dim3(768), dim3(256), 0, stream, w, wt);
  hipLaunchKernelGGL(linear_kernel, dim3(NB1 + NB3 + NB5), dim3(256), 0, stream,
                     feat, wt, out);
}